// Round 1
// baseline (311.830 us; speedup 1.0000x reference)
//
#include <hip/hip_runtime.h>

#define HIDDEN 768
#define VOCAB  32000
#define HS1    128
#define KSTEPS (HIDDEN / 32)   // 24 MFMA K-steps

typedef __attribute__((ext_vector_type(8))) short bf16x8;
typedef __attribute__((ext_vector_type(4))) float f32x4;

// fp32 -> bf16 bits, round-to-nearest-even
__device__ __forceinline__ unsigned short f2bf(float f) {
    union { float f; unsigned u; } x; x.f = f;
    unsigned r = x.u + 0x7fffu + ((x.u >> 16) & 1u);
    return (unsigned short)(r >> 16);
}

// Pack W1[VOCAB:VOCAB+768, 0:128] (fp32, row-major [in,out]) into bf16 in
// exact MFMA B-fragment order: idx = ((ks*8 + nt)*64 + lane)*8 + j
// where lane holds B[k = ks*32 + (lane>>4)*8 + j][n = nt*16 + (lane&15)].
__global__ void pack_b_kernel(const float* __restrict__ W1,
                              unsigned short* __restrict__ Bp) {
    int idx  = blockIdx.x * 256 + threadIdx.x;  // 0 .. 98303
    int j    = idx & 7;
    int lane = (idx >> 3) & 63;
    int nt   = (idx >> 9) & 7;
    int ks   = idx >> 12;                       // 0..23
    int k = ks * 32 + (lane >> 4) * 8 + j;
    int n = nt * 16 + (lane & 15);
    float v = W1[(size_t)(VOCAB + k) * HS1 + n];
    Bp[idx] = f2bf(v);
}

// One wave = 32 token rows (2 m-tiles) x N=128 (8 n-tiles), K=768.
// A direct from global (fp32 -> bf16 in reg), B from pre-packed bf16 (L2-hot).
// No LDS, no barriers. Epilogue fuses gather + b1 + relu + W2 dot + reduce.
__launch_bounds__(256, 2)
__global__ void classifier_kernel(const int* __restrict__ tk,
                                  const float* __restrict__ hs0,
                                  const float* __restrict__ W1,
                                  const float* __restrict__ b1,
                                  const float* __restrict__ W2,
                                  const float* __restrict__ b2,
                                  const unsigned short* __restrict__ Bp,
                                  float* __restrict__ out) {
    const int lane = threadIdx.x & 63;
    const int wave = threadIdx.x >> 6;      // 0..3
    const int quad = lane >> 4;             // 0..3
    const int col  = lane & 15;             // 0..15
    const int row0 = (blockIdx.x * 4 + wave) * 32;

    // A: lane holds A[m = col][k = quad*8 + j]; m-tile 1 is +16 rows.
    const float* a0 = hs0 + (size_t)(row0 + col) * HIDDEN + quad * 8;
    const float* a1 = a0 + (size_t)16 * HIDDEN;
    const unsigned short* bp = Bp + lane * 8;

    f32x4 acc[2][8];
#pragma unroll
    for (int mt = 0; mt < 2; ++mt)
#pragma unroll
        for (int nt = 0; nt < 8; ++nt)
            acc[mt][nt] = (f32x4){0.f, 0.f, 0.f, 0.f};

    struct Frag {
        f32x4 a0l, a0h, a1l, a1h;
        bf16x8 b[8];
    };

    auto load_frag = [&](int ks) {
        Frag f;
        const float* pa0 = a0 + ks * 32;
        const float* pa1 = a1 + ks * 32;
        f.a0l = *(const f32x4*)(pa0);
        f.a0h = *(const f32x4*)(pa0 + 4);
        f.a1l = *(const f32x4*)(pa1);
        f.a1h = *(const f32x4*)(pa1 + 4);
        const unsigned short* pb = bp + ks * 4096;
#pragma unroll
        for (int nt = 0; nt < 8; ++nt)
            f.b[nt] = *(const bf16x8*)(pb + nt * 512);
        return f;
    };

    auto cvt8 = [&](f32x4 lo, f32x4 hi) {
        bf16x8 r;
        r[0] = (short)f2bf(lo[0]); r[1] = (short)f2bf(lo[1]);
        r[2] = (short)f2bf(lo[2]); r[3] = (short)f2bf(lo[3]);
        r[4] = (short)f2bf(hi[0]); r[5] = (short)f2bf(hi[1]);
        r[6] = (short)f2bf(hi[2]); r[7] = (short)f2bf(hi[3]);
        return r;
    };

    auto compute = [&](const Frag& f) {
        bf16x8 af0 = cvt8(f.a0l, f.a0h);
        bf16x8 af1 = cvt8(f.a1l, f.a1h);
#pragma unroll
        for (int nt = 0; nt < 8; ++nt) {
            acc[0][nt] = __builtin_amdgcn_mfma_f32_16x16x32_bf16(af0, f.b[nt], acc[0][nt], 0, 0, 0);
            acc[1][nt] = __builtin_amdgcn_mfma_f32_16x16x32_bf16(af1, f.b[nt], acc[1][nt], 0, 0, 0);
        }
    };

    // Software-pipelined K loop, 2 frags in flight.
    Frag fa = load_frag(0);
    Frag fb = load_frag(1);
#pragma unroll 1
    for (int ks = 2; ks < KSTEPS; ks += 2) {
        compute(fa);
        fa = load_frag(ks);
        compute(fb);
        fb = load_frag(ks + 1);
    }
    compute(fa);
    compute(fb);

    // Epilogue: h = relu(acc + W1[tok] + b1); out = h . W2 + b2
    // C/D layout: n = nt*16 + col, row-in-tile = quad*4 + reg.
    const float bb2 = b2[0];
    float b1v[8], w2v[8];
#pragma unroll
    for (int nt = 0; nt < 8; ++nt) {
        b1v[nt] = b1[nt * 16 + col];
        w2v[nt] = W2[nt * 16 + col];
    }
#pragma unroll
    for (int mt = 0; mt < 2; ++mt) {
#pragma unroll
        for (int reg = 0; reg < 4; ++reg) {
            int r = row0 + mt * 16 + quad * 4 + reg;
            int token = tk[r];
            const float* wrow = W1 + (size_t)token * HS1;
            float p = 0.f;
#pragma unroll
            for (int nt = 0; nt < 8; ++nt) {
                float v = acc[mt][nt][reg] + wrow[nt * 16 + col] + b1v[nt];
                v = fmaxf(v, 0.f);
                p = fmaf(v, w2v[nt], p);
            }
            // reduce over the 16 cols held by lanes col=0..15 within this quad
            p += __shfl_xor(p, 1);
            p += __shfl_xor(p, 2);
            p += __shfl_xor(p, 4);
            p += __shfl_xor(p, 8);
            if (col == 0) out[r] = p + bb2;
        }
    }
}

extern "C" void kernel_launch(void* const* d_in, const int* in_sizes, int n_in,
                              void* d_out, int out_size, void* d_ws, size_t ws_size,
                              hipStream_t stream) {
    const int*   tk  = (const int*)d_in[0];
    const float* hs0 = (const float*)d_in[1];
    const float* W1  = (const float*)d_in[2];
    const float* b1  = (const float*)d_in[3];
    const float* W2  = (const float*)d_in[4];
    const float* b2  = (const float*)d_in[5];
    float* out = (float*)d_out;
    unsigned short* Bp = (unsigned short*)d_ws;   // 768*128*2 = 196608 B

    // Pack projection weights into bf16 MFMA-fragment order (runs every call).
    pack_b_kernel<<<(HIDDEN * HS1) / 256, 256, 0, stream>>>(W1, Bp);

    int n_tokens = in_sizes[0];        // 16*4096 = 65536
    int grid = n_tokens / 128;         // 128 rows per block (4 waves x 32)
    classifier_kernel<<<grid, 256, 0, stream>>>(tk, hs0, W1, b1, W2, b2, Bp, out);
}

// Round 2
// 304.433 us; speedup vs baseline: 1.0243x; 1.0243x over previous
//
#include <hip/hip_runtime.h>

#define HIDDEN 768
#define VOCAB  32000
#define HS1    128
#define KSTEPS (HIDDEN / 32)   // 24 MFMA K-steps

typedef __attribute__((ext_vector_type(8))) short bf16x8;
typedef __attribute__((ext_vector_type(4))) float f32x4;

// fp32 -> bf16 bits, round-to-nearest-even
__device__ __forceinline__ unsigned short f2bf(float f) {
    union { float f; unsigned u; } x; x.f = f;
    unsigned r = x.u + 0x7fffu + ((x.u >> 16) & 1u);
    return (unsigned short)(r >> 16);
}

// Pack W1[VOCAB:VOCAB+768, 0:128] (fp32, row-major [in,out]) into bf16 in
// exact MFMA B-fragment order: idx = ((ks*8 + nt)*64 + lane)*8 + j
// where lane holds B[k = ks*32 + (lane>>4)*8 + j][n = nt*16 + (lane&15)].
__global__ void pack_b_kernel(const float* __restrict__ W1,
                              unsigned short* __restrict__ Bp) {
    int idx  = blockIdx.x * 256 + threadIdx.x;  // 0 .. 98303
    int j    = idx & 7;
    int lane = (idx >> 3) & 63;
    int nt   = (idx >> 9) & 7;
    int ks   = idx >> 12;                       // 0..23
    int k = ks * 32 + (lane >> 4) * 8 + j;
    int n = nt * 16 + (lane & 15);
    float v = W1[(size_t)(VOCAB + k) * HS1 + n];
    Bp[idx] = f2bf(v);
}

// One wave = 32 token rows (2 m-tiles) x N=128 (8 n-tiles), K=768.
// A direct from global (fp32 -> bf16 in reg, nontemporal — hs0 is
// streamed exactly once; keep L2 for Bp and the W1 token gather),
// B from pre-packed bf16 (L2/L3-hot). No LDS, no barriers.
// 3-deep software pipeline to cover ~900-cyc HBM latency.
__launch_bounds__(256, 2)
__global__ void classifier_kernel(const int* __restrict__ tk,
                                  const float* __restrict__ hs0,
                                  const float* __restrict__ W1,
                                  const float* __restrict__ b1,
                                  const float* __restrict__ W2,
                                  const float* __restrict__ b2,
                                  const unsigned short* __restrict__ Bp,
                                  float* __restrict__ out) {
    const int lane = threadIdx.x & 63;
    const int wave = threadIdx.x >> 6;      // 0..3
    const int quad = lane >> 4;             // 0..3
    const int col  = lane & 15;             // 0..15
    const int row0 = (blockIdx.x * 4 + wave) * 32;

    // A: lane holds A[m = col][k = quad*8 + j]; m-tile 1 is +16 rows.
    const float* pa0 = hs0 + (size_t)(row0 + col) * HIDDEN + quad * 8;
    const float* pa1 = pa0 + (size_t)16 * HIDDEN;
    const unsigned short* pb0 = Bp + lane * 8;

    // Prefetch the 8 token ids this lane's epilogue needs (overlaps with K-loop).
    int toks[8];
#pragma unroll
    for (int mt = 0; mt < 2; ++mt)
#pragma unroll
        for (int reg = 0; reg < 4; ++reg)
            toks[mt * 4 + reg] = tk[row0 + mt * 16 + quad * 4 + reg];

    f32x4 acc[2][8];
#pragma unroll
    for (int mt = 0; mt < 2; ++mt)
#pragma unroll
        for (int nt = 0; nt < 8; ++nt)
            acc[mt][nt] = (f32x4){0.f, 0.f, 0.f, 0.f};

    struct Frag {
        f32x4 a0l, a0h, a1l, a1h;
        bf16x8 b[8];
    };

    auto load_frag = [&](int ks) {
        Frag f;
        const f32x4* x0 = (const f32x4*)(pa0 + ks * 32);
        const f32x4* x1 = (const f32x4*)(pa1 + ks * 32);
        f.a0l = __builtin_nontemporal_load(x0);
        f.a0h = __builtin_nontemporal_load(x0 + 1);
        f.a1l = __builtin_nontemporal_load(x1);
        f.a1h = __builtin_nontemporal_load(x1 + 1);
        // Two base pointers so all 8 loads use 13-bit immediate offsets.
        const unsigned short* pb  = pb0 + ks * 4096;
        const unsigned short* pb2 = pb + 2048;   // +4096 bytes
#pragma unroll
        for (int nt = 0; nt < 4; ++nt) {
            f.b[nt]     = *(const bf16x8*)(pb  + nt * 512);
            f.b[nt + 4] = *(const bf16x8*)(pb2 + nt * 512);
        }
        return f;
    };

    auto cvt8 = [&](f32x4 lo, f32x4 hi) {
        bf16x8 r;
        r[0] = (short)f2bf(lo[0]); r[1] = (short)f2bf(lo[1]);
        r[2] = (short)f2bf(lo[2]); r[3] = (short)f2bf(lo[3]);
        r[4] = (short)f2bf(hi[0]); r[5] = (short)f2bf(hi[1]);
        r[6] = (short)f2bf(hi[2]); r[7] = (short)f2bf(hi[3]);
        return r;
    };

    auto compute = [&](const Frag& f) {
        bf16x8 af0 = cvt8(f.a0l, f.a0h);
        bf16x8 af1 = cvt8(f.a1l, f.a1h);
#pragma unroll
        for (int nt = 0; nt < 8; ++nt) {
            acc[0][nt] = __builtin_amdgcn_mfma_f32_16x16x32_bf16(af0, f.b[nt], acc[0][nt], 0, 0, 0);
            acc[1][nt] = __builtin_amdgcn_mfma_f32_16x16x32_bf16(af1, f.b[nt], acc[1][nt], 0, 0, 0);
        }
    };

    // 3-deep software pipeline. KSTEPS = 24 = 3 + 7*3.
    Frag f0 = load_frag(0);
    Frag f1 = load_frag(1);
    Frag f2 = load_frag(2);
#pragma unroll 1
    for (int ks = 3; ks < KSTEPS; ks += 3) {
        compute(f0); f0 = load_frag(ks);
        compute(f1); f1 = load_frag(ks + 1);
        compute(f2); f2 = load_frag(ks + 2);
    }
    compute(f0);
    compute(f1);
    compute(f2);

    // Epilogue: h = relu(acc + W1[tok] + b1); out = h . W2 + b2
    // C/D layout: n = nt*16 + col, row-in-tile = quad*4 + reg.
    const float bb2 = b2[0];
    float b1v[8], w2v[8];
#pragma unroll
    for (int nt = 0; nt < 8; ++nt) {
        b1v[nt] = b1[nt * 16 + col];
        w2v[nt] = W2[nt * 16 + col];
    }
#pragma unroll
    for (int mt = 0; mt < 2; ++mt) {
#pragma unroll
        for (int reg = 0; reg < 4; ++reg) {
            int r = row0 + mt * 16 + quad * 4 + reg;
            const float* wrow = W1 + (size_t)toks[mt * 4 + reg] * HS1;
            float p = 0.f;
#pragma unroll
            for (int nt = 0; nt < 8; ++nt) {
                float v = acc[mt][nt][reg] + wrow[nt * 16 + col] + b1v[nt];
                v = fmaxf(v, 0.f);
                p = fmaf(v, w2v[nt], p);
            }
            // reduce over the 16 cols held by this quad's lanes
            p += __shfl_xor(p, 1);
            p += __shfl_xor(p, 2);
            p += __shfl_xor(p, 4);
            p += __shfl_xor(p, 8);
            if (col == 0) out[r] = p + bb2;
        }
    }
}

extern "C" void kernel_launch(void* const* d_in, const int* in_sizes, int n_in,
                              void* d_out, int out_size, void* d_ws, size_t ws_size,
                              hipStream_t stream) {
    const int*   tk  = (const int*)d_in[0];
    const float* hs0 = (const float*)d_in[1];
    const float* W1  = (const float*)d_in[2];
    const float* b1  = (const float*)d_in[3];
    const float* W2  = (const float*)d_in[4];
    const float* b2  = (const float*)d_in[5];
    float* out = (float*)d_out;
    unsigned short* Bp = (unsigned short*)d_ws;   // 768*128*2 = 196608 B

    // Pack projection weights into bf16 MFMA-fragment order (runs every call).
    pack_b_kernel<<<(HIDDEN * HS1) / 256, 256, 0, stream>>>(W1, Bp);

    int n_tokens = in_sizes[0];        // 16*4096 = 65536
    int grid = n_tokens / 128;         // 128 rows per block (4 waves x 32)
    classifier_kernel<<<grid, 256, 0, stream>>>(tk, hs0, W1, b1, W2, b2, Bp, out);
}

// Round 4
// 291.827 us; speedup vs baseline: 1.0685x; 1.0432x over previous
//
#include <hip/hip_runtime.h>

#define HIDDEN 768
#define VOCAB  32000
#define HS1    128
#define NSTAGE 24          // 24 stages x 32 k (one MFMA K-step per stage)
#define LSTRIDE 36         // floats per LDS row (144 B; 36 % 32 == 4 -> conflict-free b128 phases)

typedef __attribute__((ext_vector_type(8))) short bf16x8;
typedef __attribute__((ext_vector_type(4))) float f32x4;

// fp32 -> bf16 bits, round-to-nearest-even
__device__ __forceinline__ unsigned short f2bf(float f) {
    union { float f; unsigned u; } x; x.f = f;
    unsigned r = x.u + 0x7fffu + ((x.u >> 16) & 1u);
    return (unsigned short)(r >> 16);
}

// Pack W1[VOCAB:VOCAB+768, 0:128] into bf16 MFMA B-fragment order.
// Coalesced contiguous READ of W1 (the latency-sensitive side), scattered
// 2-B writes (fire-and-forget). Bp[((ks*8+nt)*64+lane)*8+j] =
// B[k=ks*32+(lane>>4)*8+j][n=nt*16+(lane&15)].
__global__ void pack_b_kernel(const float* __restrict__ W1,
                              unsigned short* __restrict__ Bp) {
    int tid = blockIdx.x * 256 + threadIdx.x;   // 0 .. 98303
    float v = W1[(size_t)VOCAB * HS1 + tid];
    int k = tid >> 7;                            // 0..767
    int n = tid & 127;
    int ks = k >> 5, kr = k & 31;
    int quad = kr >> 3, j = kr & 7;
    int nt = n >> 4, c = n & 15;
    int lane = quad * 16 + c;
    Bp[(((ks * 8 + nt) * 64 + lane) << 3) + j] = f2bf(v);
}

// One wave = 32 token rows (2 m-tiles) x N=128 (8 n-tiles), K=768.
// hs0 staged via wave-private double-buffered LDS with perfectly coalesced
// global loads (8 consecutive lanes = 128 B contiguous; every byte of every
// fetched line consumed by the issuing instruction -> nontemporal is safe
// and keeps Bp/W1 resident in L2). A-fragments via conflict-free
// ds_read_b128. No barriers (per-wave in-order LDS orders w->r).
__launch_bounds__(256, 2)
__global__ void classifier_kernel(const int* __restrict__ tk,
                                  const float* __restrict__ hs0,
                                  const float* __restrict__ W1,
                                  const float* __restrict__ b1,
                                  const float* __restrict__ W2,
                                  const float* __restrict__ b2,
                                  const unsigned short* __restrict__ Bp,
                                  float* __restrict__ out) {
    __shared__ float lds[4][2][32 * LSTRIDE];   // 36864 B / block

    const int lane = threadIdx.x & 63;
    const int wave = threadIdx.x >> 6;      // 0..3
    const int quad = lane >> 4;             // 0..3
    const int col  = lane & 15;             // 0..15
    const int row0 = (blockIdx.x * 4 + wave) * 32;

    float* buf0 = &lds[wave][0][0];
    float* buf1 = &lds[wave][1][0];

    // Staging mapping: instr i (0..3), lane l -> row = i*8 + (l>>3),
    // float offset (l&7)*4. 8 consecutive lanes cover one row's 128-B slab.
    const int srow = lane >> 3;             // 0..7
    const int scol = (lane & 7) * 4;        // 0,4,..,28
    const float* gbase = hs0 + (size_t)row0 * HIDDEN;

    // Prefetch the 8 token ids this lane's epilogue needs.
    int toks[8];
#pragma unroll
    for (int mt = 0; mt < 2; ++mt)
#pragma unroll
        for (int reg = 0; reg < 4; ++reg)
            toks[mt * 4 + reg] = tk[row0 + mt * 16 + quad * 4 + reg];

    f32x4 acc[2][8];
#pragma unroll
    for (int mt = 0; mt < 2; ++mt)
#pragma unroll
        for (int nt = 0; nt < 8; ++nt)
            acc[mt][nt] = (f32x4){0.f, 0.f, 0.f, 0.f};

    f32x4 greg[4];
    auto gload = [&](int s) {
#pragma unroll
        for (int i = 0; i < 4; ++i) {
            const float* p = gbase + (size_t)(i * 8 + srow) * HIDDEN + s * 32 + scol;
            greg[i] = __builtin_nontemporal_load((const f32x4*)p);
        }
    };
    auto lstore = [&](float* buf) {
#pragma unroll
        for (int i = 0; i < 4; ++i)
            *(f32x4*)(buf + (i * 8 + srow) * LSTRIDE + scol) = greg[i];
    };

    const unsigned short* pb0 = Bp + lane * 8;
    auto loadB = [&](int kstep, bf16x8* b) {
        const unsigned short* pb = pb0 + kstep * 4096;
#pragma unroll
        for (int nt = 0; nt < 4; ++nt) {
            b[nt]     = *(const bf16x8*)(pb + nt * 512);
            b[nt + 4] = *(const bf16x8*)(pb + 2048 + nt * 512);
        }
    };

    auto cvt8 = [&](f32x4 lo, f32x4 hi) {
        bf16x8 r;
        r[0] = (short)f2bf(lo[0]); r[1] = (short)f2bf(lo[1]);
        r[2] = (short)f2bf(lo[2]); r[3] = (short)f2bf(lo[3]);
        r[4] = (short)f2bf(hi[0]); r[5] = (short)f2bf(hi[1]);
        r[6] = (short)f2bf(hi[2]); r[7] = (short)f2bf(hi[3]);
        return r;
    };

    auto stage_body = [&](int s, float* cur, float* alt,
                          const bf16x8* bc, bf16x8* bn) {
        if (s + 1 < NSTAGE) loadB(s + 1, bn);
        if (s + 1 < NSTAGE) lstore(alt);       // greg holds stage s+1
        if (s + 2 < NSTAGE) gload(s + 2);
        // A fragments: lane -> A[m=col][k=quad*8+j], m-tile 1 at +16 rows.
        const float* p0 = cur + col * LSTRIDE + quad * 8;
        const float* p1 = p0 + 16 * LSTRIDE;
        f32x4 a0l = *(const f32x4*)p0, a0h = *(const f32x4*)(p0 + 4);
        f32x4 a1l = *(const f32x4*)p1, a1h = *(const f32x4*)(p1 + 4);
        bf16x8 af0 = cvt8(a0l, a0h);
        bf16x8 af1 = cvt8(a1l, a1h);
#pragma unroll
        for (int nt = 0; nt < 8; ++nt) {
            acc[0][nt] = __builtin_amdgcn_mfma_f32_16x16x32_bf16(af0, bc[nt], acc[0][nt], 0, 0, 0);
            acc[1][nt] = __builtin_amdgcn_mfma_f32_16x16x32_bf16(af1, bc[nt], acc[1][nt], 0, 0, 0);
        }
    };

    // Prologue: stage 0 -> buf0; stage 1 in greg; K-step 0 B in flight.
    // (bfrA/bfrB: must NOT be named b0/b1 — parameter-name collision in the
    //  outermost block is ill-formed and caused R3's compile failure.)
    bf16x8 bfrA[8], bfrB[8];
    gload(0);
    lstore(buf0);
    gload(1);
    loadB(0, bfrA);

#pragma unroll 1
    for (int s = 0; s < NSTAGE; s += 2) {
        stage_body(s,     buf0, buf1, bfrA, bfrB);
        stage_body(s + 1, buf1, buf0, bfrB, bfrA);
    }

    // Epilogue: h = relu(acc + W1[tok] + b1); out = h . W2 + b2
    // C/D layout: n = nt*16 + col, row-in-tile = quad*4 + reg.
    const float bb2 = b2[0];
    float b1v[8], w2v[8];
#pragma unroll
    for (int nt = 0; nt < 8; ++nt) {
        b1v[nt] = b1[nt * 16 + col];
        w2v[nt] = W2[nt * 16 + col];
    }
#pragma unroll
    for (int mt = 0; mt < 2; ++mt) {
#pragma unroll
        for (int reg = 0; reg < 4; ++reg) {
            int r = row0 + mt * 16 + quad * 4 + reg;
            const float* wrow = W1 + (size_t)toks[mt * 4 + reg] * HS1;
            float p = 0.f;
#pragma unroll
            for (int nt = 0; nt < 8; ++nt) {
                float v = acc[mt][nt][reg] + wrow[nt * 16 + col] + b1v[nt];
                v = fmaxf(v, 0.f);
                p = fmaf(v, w2v[nt], p);
            }
            p += __shfl_xor(p, 1);
            p += __shfl_xor(p, 2);
            p += __shfl_xor(p, 4);
            p += __shfl_xor(p, 8);
            if (col == 0) out[r] = p + bb2;
        }
    }
}

extern "C" void kernel_launch(void* const* d_in, const int* in_sizes, int n_in,
                              void* d_out, int out_size, void* d_ws, size_t ws_size,
                              hipStream_t stream) {
    const int*   tk  = (const int*)d_in[0];
    const float* hs0 = (const float*)d_in[1];
    const float* W1  = (const float*)d_in[2];
    const float* b1  = (const float*)d_in[3];
    const float* W2  = (const float*)d_in[4];
    const float* b2  = (const float*)d_in[5];
    float* out = (float*)d_out;
    unsigned short* Bp = (unsigned short*)d_ws;   // 768*128*2 = 196608 B

    pack_b_kernel<<<(HIDDEN * HS1) / 256, 256, 0, stream>>>(W1, Bp);

    int n_tokens = in_sizes[0];        // 16*4096 = 65536
    int grid = n_tokens / 128;         // 128 rows per block (4 waves x 32)
    classifier_kernel<<<grid, 256, 0, stream>>>(tk, hs0, W1, b1, W2, b2, Bp, out);
}